// Round 15
// baseline (146.424 us; speedup 1.0000x reference)
//
#include <hip/hip_runtime.h>
#include <cstddef>

// ---------------------------------------------------------------------------
// MHA block: y = attn(x@Wqkv+b) @ Wo + bo   (B=16,T=512,C=1024,H=16,hd=64)
// R15: QKV rebuilt on the m201 8-phase 256x256 template (8 waves 2Mx4N,
// wave 128x64, A dbuf + B TRIbuf = 160KB LDS, per-phase {reads; 2-issue
// stage; bar; lgkm0; 16 MFMA; bar}, counted vmcnt(8)/tile). Everything
// else frozen from R14 (attn R13, out-proj R14, cvt, tconv).
// ---------------------------------------------------------------------------

#define B_  16
#define T_  512
#define C_  1024
#define H_  16
#define HD_ 64

typedef __bf16 bf16x8 __attribute__((ext_vector_type(8)));
typedef float  f32x4  __attribute__((ext_vector_type(4)));

__device__ __forceinline__ void gload16(const void* g, void* lds_dst) {
  __builtin_amdgcn_global_load_lds(
      (const __attribute__((address_space(1))) unsigned int*)g,
      (__attribute__((address_space(3))) unsigned int*)lds_dst, 16, 0, 0);
}

// ------------------------- convert x: fp32 -> bf16 --------------------------
__global__ void cvt_kernel(const float* __restrict__ in, __bf16* __restrict__ out, int n) {
  int i = (blockIdx.x * 256 + threadIdx.x) * 8;
  if (i >= n) return;
  float4 f0 = *(const float4*)&in[i];
  float4 f1 = *(const float4*)&in[i + 4];
  bf16x8 o;
  o[0] = (__bf16)f0.x; o[1] = (__bf16)f0.y; o[2] = (__bf16)f0.z; o[3] = (__bf16)f0.w;
  o[4] = (__bf16)f1.x; o[5] = (__bf16)f1.y; o[6] = (__bf16)f1.z; o[7] = (__bf16)f1.w;
  *(bf16x8*)&out[i] = o;
}

// -------------- transpose+convert: w[K][N] fp32 -> wt[N][K] bf16 ------------
__global__ void tconv_kernel(const float* __restrict__ w, __bf16* __restrict__ wt,
                             int K, int N) {
  __shared__ float tile[32][33];
  int tx = threadIdx.x, ty = threadIdx.y;          // block (32,8)
  int n0 = blockIdx.x * 32, k0 = blockIdx.y * 32;
  #pragma unroll
  for (int i = 0; i < 4; ++i) {
    int r = ty + i * 8;
    tile[r][tx] = w[(size_t)(k0 + r) * N + n0 + tx];
  }
  __syncthreads();
  #pragma unroll
  for (int i = 0; i < 4; ++i) {
    int r = ty + i * 8;
    wt[(size_t)(n0 + r) * K + k0 + tx] = (__bf16)tile[tx][r];
  }
}

// ---------------------------------------------------------------------------
// QKV GEMM, 8-phase m201 template. Tile 256x256, BK=64, 512 thr, 8 waves
// (2M x 4N), per-wave 128x64 (8x4 16x16 frags). LDS 160KB: A dbuf 2x32KB,
// B tribuf 3x32KB. Granule-XOR swizzle (g ^= row&7) via pre-swizzled global
// source; linear gload_lds dest.
// Per K-tile t (Abuf t&1, Bbuf t%3), 4 phases, each:
//   {ds_reads ; 2-issue stage ; [lgkm8 if 12 reads] ; s_barrier ;
//    lgkmcnt(0)+sched_barrier ; setprio(1) 16 MFMA setprio(0) ; s_barrier}
//   ph0: rdA a0(8)+rdB b0(4) ; stage B(t+2) slabs{0,1}   ; mfma (0,0)
//   ph1: rdB b1(4)           ; stage B(t+2) slabs{2,3}   ; mfma (0,1)
//   ph2: rdA a1(8)           ; stage A(t+2) slabs{0,2}   ; mfma (1,0)
//   ph3: none                ; stage A(t+2) slabs{1,3}   ; mfma (1,1)
//   tile end: vmcnt(8) (or 0 if no stages issued) + barrier.
// Hazard audit: B(t+2) -> tribuf slot read in tile t-1 (>=4 barriers) OK.
// A(t+2) slabs{0,2} = rows {0-63,128-191} = EXACTLY ph0's read set (both
// wm), retired at ph0's lgkm0, >=2 barriers before ph2's stage; ph2's own
// reads are slabs{1,3} - address-disjoint. A slabs{1,3} = ph2's read set,
// staged in ph3 after ph2's lgkm0+barrier. vmcnt(8) at tile end keeps the
// current tile's 8 issues in flight, drains t-1's -> t+1's data landed.
// ---------------------------------------------------------------------------
__global__ __launch_bounds__(512, 2) void gemmq8_kernel(
    const __bf16* __restrict__ A, const __bf16* __restrict__ BT,
    const float* __restrict__ bias, int K, int NBn,
    __bf16* __restrict__ oq, __bf16* __restrict__ okk, __bf16* __restrict__ ovt)
{
  extern __shared__ __align__(16) char lds[];
  const int tid = threadIdx.x, lane = tid & 63, wid = tid >> 6;  // 8 waves
  const int wm = wid >> 2, wn = wid & 3;          // 2M x 4N
  const int lr = lane & 15, lg = lane >> 4;

  const int cpx = gridDim.x >> 3;                 // bijective XCD swizzle
  const int id = (blockIdx.x & 7) * cpx + (blockIdx.x >> 3);
  const int m0 = (id / NBn) * 256, n0 = (id % NBn) * 256;

  // staging: one issue = 512 lanes x 16B = 8KB = 64 rows (a "slab")
  const int r8  = tid >> 3;                       // 0..63 row in slab
  const int csw = ((tid & 7) ^ ((tid >> 3) & 7)) * 8;  // pre-swizzled col

  auto stage_slabs = [&](const __bf16* g, char* dst, int s0, int s1) {
    gload16(g + (size_t)(s0 * 64 + r8) * K + csw, dst + s0 * 8192 + wid * 1024);
    gload16(g + (size_t)(s1 * 64 + r8) * K + csw, dst + s1 * 8192 + wid * 1024);
  };

  auto rdA = [&](bf16x8* d, const char* Ab, int mh) {   // 8 x ds_read_b128
    #pragma unroll
    for (int f = 0; f < 4; ++f) {
      const char* rp = Ab + (wm * 128 + (mh * 4 + f) * 16 + lr) * 128;
      #pragma unroll
      for (int ks = 0; ks < 2; ++ks)
        d[f * 2 + ks] = *(const bf16x8*)(rp + (((ks << 2) + lg) ^ (lr & 7)) * 16);
    }
  };
  auto rdB = [&](bf16x8* d, const char* Bb, int nh) {   // 4 x ds_read_b128
    #pragma unroll
    for (int f = 0; f < 2; ++f) {
      const char* rp = Bb + (wn * 64 + (nh * 2 + f) * 16 + lr) * 128;
      #pragma unroll
      for (int ks = 0; ks < 2; ++ks)
        d[f * 2 + ks] = *(const bf16x8*)(rp + (((ks << 2) + lg) ^ (lr & 7)) * 16);
    }
  };

  f32x4 acc[8][4] = {};

  auto mmq = [&](int mh, int nh, const bf16x8* av, const bf16x8* bv) { // 16 MFMA
    __builtin_amdgcn_s_setprio(1);
    #pragma unroll
    for (int f = 0; f < 4; ++f)
      #pragma unroll
      for (int g2 = 0; g2 < 2; ++g2)
        #pragma unroll
        for (int ks = 0; ks < 2; ++ks)
          acc[mh * 4 + f][nh * 2 + g2] = __builtin_amdgcn_mfma_f32_16x16x32_bf16(
              av[f * 2 + ks], bv[g2 * 2 + ks], acc[mh * 4 + f][nh * 2 + g2], 0, 0, 0);
    __builtin_amdgcn_s_setprio(0);
  };

#define PH_MID() do {                                                        \
    asm volatile("s_barrier\ns_waitcnt lgkmcnt(0)" ::: "memory");            \
    __builtin_amdgcn_sched_barrier(0); } while (0)
#define PH_END() asm volatile("s_barrier" ::: "memory")

  const int nt = K >> 6;                          // 16
  const __bf16* gA = A  + (size_t)m0 * K;
  const __bf16* gB = BT + (size_t)n0 * K;
  char* const A0b = lds;                          // 2 x 32KB
  char* const A1b = lds + 32768;
  char* const Bb0 = lds + 65536;                  // 3 x 32KB

  // prologue: B(0), A(0), B(1), A(1)  (16 issues; oldest 8 = tile 0)
  stage_slabs(gB, Bb0, 0, 1);           stage_slabs(gB, Bb0, 2, 3);
  stage_slabs(gA, A0b, 0, 1);           stage_slabs(gA, A0b, 2, 3);
  stage_slabs(gB + 64, Bb0 + 32768, 0, 1); stage_slabs(gB + 64, Bb0 + 32768, 2, 3);
  stage_slabs(gA + 64, A1b, 0, 1);      stage_slabs(gA + 64, A1b, 2, 3);
  asm volatile("s_waitcnt vmcnt(8)\ns_barrier" ::: "memory");

  bf16x8 a0[8], a1[8], b0[4], b1[4];

  for (int t = 0; t < nt; ++t) {
    char* const Ab = (t & 1) ? A1b : A0b;
    char* const Bb = Bb0 + (t % 3) * 32768;
    char* const Bw = Bb0 + ((t + 2) % 3) * 32768;
    const __bf16* gA2 = gA + (size_t)(t + 2) * 64;
    const __bf16* gB2 = gB + (size_t)(t + 2) * 64;
    const bool st = (t + 2 < nt);

    // ---- ph0: reads a0(8)+b0(4); stage B(t+2){0,1}; mfma (0,0) ----
    rdA(a0, Ab, 0);
    rdB(b0, Bb, 0);
    if (st) stage_slabs(gB2, Bw, 0, 1);
    asm volatile("s_waitcnt lgkmcnt(8)" ::: "memory");
    PH_MID();
    mmq(0, 0, a0, b0);
    PH_END();

    // ---- ph1: reads b1(4); stage B(t+2){2,3}; mfma (0,1) ----
    rdB(b1, Bb, 1);
    if (st) stage_slabs(gB2, Bw, 2, 3);
    PH_MID();
    mmq(0, 1, a0, b1);
    PH_END();

    // ---- ph2: reads a1(8); stage A(t+2){0,2}; mfma (1,0) ----
    rdA(a1, Ab, 1);
    if (st) stage_slabs(gA2, Ab, 0, 2);
    PH_MID();
    mmq(1, 0, a1, b0);
    PH_END();

    // ---- ph3: stage A(t+2){1,3}; mfma (1,1); tile-end counted vmcnt ----
    if (st) stage_slabs(gA2, Ab, 1, 3);
    PH_MID();
    mmq(1, 1, a1, b1);
    if (st) { asm volatile("s_waitcnt vmcnt(8)\ns_barrier" ::: "memory"); }
    else    { asm volatile("s_waitcnt vmcnt(0)\ns_barrier" ::: "memory"); }
  }
#undef PH_MID
#undef PH_END

  // ---- epilogue: split q/k/v; Q pre-scaled; V direct-transposed ----
  const float QSC = 0.04508422f;                  // 2^-5 * log2(e)
  #pragma unroll
  for (int nf = 0; nf < 4; ++nf) {
    int n = n0 + wn * 64 + nf * 16 + lr;
    float bv = bias[n];
    int which = n >> 10;
    int h = (n >> 6) & 15, d = n & 63;
    if (which == 2) {
      #pragma unroll
      for (int mf = 0; mf < 8; ++mf) {
        int m = m0 + wm * 128 + mf * 16 + lg * 4;     // j=0 row
        int bb = m >> 9, t0 = m & 511;
        ushort4 pk;
        __bf16 e0 = (__bf16)(acc[mf][nf][0] + bv);
        __bf16 e1 = (__bf16)(acc[mf][nf][1] + bv);
        __bf16 e2 = (__bf16)(acc[mf][nf][2] + bv);
        __bf16 e3 = (__bf16)(acc[mf][nf][3] + bv);
        pk.x = *(unsigned short*)&e0; pk.y = *(unsigned short*)&e1;
        pk.z = *(unsigned short*)&e2; pk.w = *(unsigned short*)&e3;
        *(ushort4*)&ovt[(size_t)((bb * H_ + h) * HD_ + d) * T_ + t0] = pk;
      }
    } else {
      __bf16* dst = (which == 0) ? oq : okk;
      const float scl = (which == 0) ? QSC : 1.0f;
      #pragma unroll
      for (int mf = 0; mf < 8; ++mf)
        #pragma unroll
        for (int j = 0; j < 4; ++j) {
          int m = m0 + wm * 128 + mf * 16 + lg * 4 + j;
          int bb = m >> 9, tt = m & 511;
          dst[(size_t)((bb * H_ + h) * T_ + tt) * HD_ + d] =
              (__bf16)((acc[mf][nf][j] + bv) * scl);
        }
    }
  }
}

// ---------------------------------------------------------------------------
// Out-proj GEMM (R14-frozen): tile 64x128, 4 waves, LDS 24KB, grid 1024.
// ---------------------------------------------------------------------------
__global__ __launch_bounds__(256) void gemmsq_o_kernel(
    const __bf16* __restrict__ A, const __bf16* __restrict__ BT,
    const float* __restrict__ bias, int K, int NBn, int N,
    float* __restrict__ out32)
{
  __shared__ __attribute__((aligned(16))) char lds[24576];   // A 8KB | B 16KB
  const int tid = threadIdx.x, lane = tid & 63, wid = tid >> 6;
  const int wm = wid >> 1, wn = wid & 1;          // 2M x 2N
  const int lr = lane & 15, lg = lane >> 4;

  const int cpx = gridDim.x >> 3;
  const int id = (blockIdx.x & 7) * cpx + (blockIdx.x >> 3);
  const int m0 = (id / NBn) * 64, n0 = (id % NBn) * 128;

  const int r8  = wid * 8 + (lane >> 3);          // 0..31
  const int csw = ((lane & 7) ^ (lane >> 3)) * 8;

  auto stageA = [&](const __bf16* g, char* dst) { // 64x64 tile, 2 issues
    #pragma unroll
    for (int i = 0; i < 2; ++i)
      gload16(g + (size_t)(i * 32 + r8) * K + csw, dst + i * 4096 + wid * 1024);
  };
  auto stageB = [&](const __bf16* g, char* dst) { // 128x64 tile, 4 issues
    #pragma unroll
    for (int i = 0; i < 4; ++i)
      gload16(g + (size_t)(i * 32 + r8) * K + csw, dst + i * 4096 + wid * 1024);
  };
  auto rdA = [&](bf16x8* d, const char* buf) {    // 4 x ds_read_b128
    #pragma unroll
    for (int f = 0; f < 2; ++f) {
      const char* rp = buf + (wm * 32 + f * 16 + lr) * 128;
      #pragma unroll
      for (int ks = 0; ks < 2; ++ks)
        d[f * 2 + ks] = *(const bf16x8*)(rp + (((ks << 2) + lg) ^ (lr & 7)) * 16);
    }
  };
  auto rdB = [&](bf16x8* d, const char* buf) {    // 8 x ds_read_b128
    #pragma unroll
    for (int f = 0; f < 4; ++f) {
      const char* rp = buf + (wn * 64 + f * 16 + lr) * 128;
      #pragma unroll
      for (int ks = 0; ks < 2; ++ks)
        d[f * 2 + ks] = *(const bf16x8*)(rp + (((ks << 2) + lg) ^ (lr & 7)) * 16);
    }
  };

  f32x4 acc[2][4] = {};
  const int nt = K >> 6;
  const __bf16* gA = A  + (size_t)m0 * K;
  const __bf16* gB = BT + (size_t)n0 * K;
  char* const Ab = lds;
  char* const Bb = lds + 8192;

  stageA(gA, Ab);
  stageB(gB, Bb);
  asm volatile("s_waitcnt vmcnt(0)\ns_barrier" ::: "memory");

  bf16x8 a[4], b[8];
  for (int t = 0; t < nt; ++t) {
    rdA(a, Ab);
    rdB(b, Bb);
    asm volatile("s_waitcnt lgkmcnt(0)\ns_barrier" ::: "memory");
    if (t + 1 < nt) {
      stageA(gA + (size_t)(t + 1) * 64, Ab);
      stageB(gB + (size_t)(t + 1) * 64, Bb);
    }
    __builtin_amdgcn_s_setprio(1);
    #pragma unroll
    for (int mf = 0; mf < 2; ++mf)
      #pragma unroll
      for (int nf = 0; nf < 4; ++nf)
        #pragma unroll
        for (int ks = 0; ks < 2; ++ks)
          acc[mf][nf] = __builtin_amdgcn_mfma_f32_16x16x32_bf16(
              a[mf * 2 + ks], b[nf * 2 + ks], acc[mf][nf], 0, 0, 0);
    __builtin_amdgcn_s_setprio(0);
    asm volatile("s_waitcnt vmcnt(0)\ns_barrier" ::: "memory");
  }

  #pragma unroll
  for (int nf = 0; nf < 4; ++nf) {
    int n = n0 + wn * 64 + nf * 16 + lr;
    float bv = bias[n];
    #pragma unroll
    for (int mf = 0; mf < 2; ++mf)
      #pragma unroll
      for (int j = 0; j < 4; ++j) {
        int m = m0 + wm * 32 + mf * 16 + lg * 4 + j;
        out32[(size_t)m * N + n] = acc[mf][nf][j] + bv;
      }
  }
}

// ---------------------------------------------------------------------------
// Flash attention (causal), full-LDS per-head (R13-frozen).
// ---------------------------------------------------------------------------
__global__ __launch_bounds__(512) void attn_kernel(
    const __bf16* __restrict__ qb, const __bf16* __restrict__ kb,
    const __bf16* __restrict__ vtb, __bf16* __restrict__ y)
{
  extern __shared__ __align__(16) char smem[];
  char* const Ksb = smem;                         // 64KB  K  [512][64]
  char* const Vtb = smem + 65536;                 // 64KB  V^T [64][512]
  char* const Psb = smem + 131072;                // 32KB  [8w][2g][16][64] swz

  const int tid = threadIdx.x, lane = tid & 63, w = tid >> 6;   // 8 waves
  const int lr = lane & 15, lg = lane >> 4;
  const int bh = blockIdx.x;
  const size_t base = (size_t)bh * T_ * HD_;
  const int b = bh >> 4, h = bh & 15;

  {
    const int rk = tid >> 3;
    const int sk = (tid & 7) ^ (rk & 7);
    const int rv = tid >> 6;
    const int sv = (tid & 63) ^ rv;
    #pragma unroll
    for (int i = 0; i < 8; ++i) {
      gload16(kb  + base + (size_t)(i * 64 + rk) * HD_ + sk * 8,
              Ksb + i * 8192 + w * 1024);
      gload16(vtb + base + (size_t)(i * 8 + rv) * T_ + sv * 8,
              Vtb + i * 8192 + w * 1024);
    }
  }
  asm volatile("s_waitcnt vmcnt(0)\ns_barrier" ::: "memory");

  bf16x8 onesf;
  #pragma unroll
  for (int i = 0; i < 8; ++i) onesf[i] = (__bf16)1.0f;

  char* const PsW0 = Psb + (w * 2 + 0) * 2048;
  char* const PsW1 = Psb + (w * 2 + 1) * 2048;

  #pragma unroll 1
  for (int sw = 0; sw < 2; ++sw) {
    const int GA = sw * 16 + w;
    const int GB = sw * 16 + 15 - w;
    const int q0A = GA * 16, q0B = GB * 16;
    const int cA = GA >> 2, cB = GB >> 2;

    bf16x8 qfA[2], qfB[2];
    #pragma unroll
    for (int s = 0; s < 2; ++s) {
      qfA[s] = *(const bf16x8*)&qb[base + (size_t)(q0A + lr) * HD_ + s * 32 + lg * 8];
      qfB[s] = *(const bf16x8*)&qb[base + (size_t)(q0B + lr) * HD_ + s * 32 + lg * 8];
    }

    f32x4 accA[4] = {}, accB[4] = {};
    f32x4 saccA = {}, saccB = {};

    for (int c = 0; c <= cB; ++c) {
      const bool actA = (c <= cA);

      bf16x8 kf[2][4];
      #pragma unroll
      for (int s = 0; s < 2; ++s)
        #pragma unroll
        for (int cc = 0; cc < 4; ++cc)
          kf[s][cc] = *(const bf16x8*)(Ksb + (size_t)(c * 64 + cc * 16 + lr) * 128
                                       + (((s << 2) + lg) ^ (lr & 7)) * 16);

      #pragma unroll
      for (int g = 0; g < 2; ++g) {
        if (g == 0 && !actA) continue;
        const bf16x8* qf = (g == 0) ? qfA : qfB;
        const int q0 = (g == 0) ? q0A : q0B;
        const int cg = (g == 0) ? cA : cB;
        char* PsW = (g == 0) ? PsW0 : PsW1;

        f32x4 sc[4] = {};
        __builtin_amdgcn_s_setprio(1);
        #pragma unroll
        for (int s = 0; s < 2; ++s)
          #pragma unroll
          for (int cc = 0; cc < 4; ++cc)
            sc[cc] = __builtin_amdgcn_mfma_f32_16x16x32_bf16(
                kf[s][cc], qf[s], sc[cc], 0, 0, 0);
        __builtin_amdgcn_s_setprio(0);

        #pragma unroll
        for (int cc = 0; cc < 4; ++cc) {
          float p[4];
          #pragma unroll
          for (int j = 0; j < 4; ++j) {
            float v = exp2f(sc[cc][j]);
            if (c == cg) {
              int kv = c * 64 + cc * 16 + lg * 4 + j;
              if (kv > q0 + lr) v = 0.f;
            }
            p[j] = v;
          }
          ushort4 pkw;
          __bf16 e0 = (__bf16)p[0], e1 = (__bf16)p[1];
          __bf16 e2 = (__bf16)p[2], e3 = (__bf16)p[3];
          pkw.x = *(unsigned short*)&e0; pkw.y = *(unsigned short*)&e1;
          pkw.z = *(unsigned short*)&e2; pkw.w = *(unsigned short*)&e3;
          int g16 = (2 * cc + (lg >> 1)) ^ (lr & 7);
          *(ushort4*)(PsW + lr * 128 + g16 * 16 + (lg & 1) * 8) = pkw;
        }
      }

      bf16x8 vf[2][4];
      #pragma unroll
      for (int s = 0; s < 2; ++s)
        #pragma unroll
        for (int dd = 0; dd < 4; ++dd)
          vf[s][dd] = *(const bf16x8*)(Vtb + (size_t)(dd * 16 + lr) * 1024
                                       + (8 * c + (((s << 2) + lg) ^ (lr & 7))) * 16);

      __builtin_amdgcn_s_setprio(1);
      #pragma unroll
      for (int g = 0; g < 2; ++g) {
        if (g == 0 && !actA) continue;
        char* PsW = (g == 0) ? PsW0 : PsW1;
        f32x4* acc = (g == 0) ? accA : accB;
        f32x4& sacc = (g == 0) ? saccA : saccB;
        #pragma unroll
        for (int s = 0; s < 2; ++s) {
          bf16x8 pa = *(const bf16x8*)(PsW + lr * 128
                                       + (((s << 2) + lg) ^ (lr & 7)) * 16);
          sacc = __builtin_amdgcn_mfma_f32_16x16x32_bf16(pa, onesf, sacc, 0, 0, 0);
          #pragma unroll
          for (int dd = 0; dd < 4; ++dd)
            acc[dd] = __builtin_amdgcn_mfma_f32_16x16x32_bf16(
                pa, vf[s][dd], acc[dd], 0, 0, 0);
        }
      }
      __builtin_amdgcn_s_setprio(0);
    }

    #pragma unroll
    for (int g = 0; g < 2; ++g) {
      const int q0 = (g == 0) ? q0A : q0B;
      f32x4* acc = (g == 0) ? accA : accB;
      f32x4& sacc = (g == 0) ? saccA : saccB;
      float inv[4];
      #pragma unroll
      for (int j = 0; j < 4; ++j) inv[j] = 1.f / sacc[j];
      #pragma unroll
      for (int dd = 0; dd < 4; ++dd)
        #pragma unroll
        for (int j = 0; j < 4; ++j) {
          int t = q0 + lg * 4 + j;
          int d = dd * 16 + lr;
          y[((size_t)(b * T_ + t)) * C_ + h * HD_ + d] = (__bf16)(acc[dd][j] * inv[j]);
        }
    }
  }
}

// ---------------------------------------------------------------------------
extern "C" void kernel_launch(void* const* d_in, const int* in_sizes, int n_in,
                              void* d_out, int out_size, void* d_ws, size_t ws_size,
                              hipStream_t stream) {
  const float* x    = (const float*)d_in[0];
  const float* wqkv = (const float*)d_in[1];
  const float* bqkv = (const float*)d_in[2];
  const float* wo   = (const float*)d_in[3];
  const float* bo   = (const float*)d_in[4];
  float* out = (float*)d_out;

  char* ws = (char*)d_ws;
  const size_t MB = 1u << 20;
  __bf16* xb    = (__bf16*)(ws);              // 16 MB  x bf16 [8192][1024]
  __bf16* wqt   = (__bf16*)(ws + 16 * MB);    //  6 MB  w_qkv^T bf16 [3072][1024]
  __bf16* wot   = (__bf16*)(ws + 22 * MB);    //  2 MB  w_o^T bf16 [1024][1024]
  __bf16* qbuf  = (__bf16*)(ws + 24 * MB);    // 16 MB  Q' [B,H,T,HD] (pre-scaled)
  __bf16* kbuf  = (__bf16*)(ws + 40 * MB);    // 16 MB  K [B,H,T,HD]
  __bf16* vtbuf = (__bf16*)(ws + 56 * MB);    // 16 MB  V^T [B,H,HD,T] (direct)
  __bf16* ybuf  = (__bf16*)(ws + 72 * MB);    // 16 MB  attn out [B,T,C]

  (void)hipFuncSetAttribute(reinterpret_cast<const void*>(&attn_kernel),
                            hipFuncAttributeMaxDynamicSharedMemorySize, 163840);
  (void)hipFuncSetAttribute(reinterpret_cast<const void*>(&gemmq8_kernel),
                            hipFuncAttributeMaxDynamicSharedMemorySize, 163840);

  const int NX = B_ * T_ * C_;               // 8388608
  cvt_kernel<<<NX / (256 * 8), 256, 0, stream>>>(x, xb, NX);
  tconv_kernel<<<dim3(3 * C_ / 32, C_ / 32), dim3(32, 8), 0, stream>>>(wqkv, wqt, C_, 3 * C_);
  tconv_kernel<<<dim3(C_ / 32, C_ / 32), dim3(32, 8), 0, stream>>>(wo, wot, C_, C_);

  // QKV: 32 x 12 = 384 blocks (8-phase 256x256 template)
  gemmq8_kernel<<<384, 512, 163840, stream>>>(
      xb, wqt, bqkv, C_, 12, qbuf, kbuf, vtbuf);

  // attention: one block/head, full K/V^T in LDS, batched swapped-QK waves
  attn_kernel<<<256, 512, 163840, stream>>>(qbuf, kbuf, vtbuf, ybuf);

  // out-proj: 128 x 8 -> 1024 blocks (64x128 tile)
  gemmsq_o_kernel<<<1024, 256, 0, stream>>>(
      ybuf, wot, bo, C_, 8, C_, out);
}

// Round 16
// 120.847 us; speedup vs baseline: 1.2117x; 1.2117x over previous
//
#include <hip/hip_runtime.h>
#include <cstddef>

// ---------------------------------------------------------------------------
// MHA block: y = attn(x@Wqkv+b) @ Wo + bo   (B=16,T=512,C=1024,H=16,hd=64)
// R16: QKV reverted to the proven m97 gemmsq (R15's 8-phase port failed:
// K=1024 = 16 tiles can't amortize 8 barriers/tile; 256^2 tile = 1.5-round
// packing). NEW: cvt + both tconvs fused into one prep_kernel (one
// dispatch, shared HBM streams). attn R13 / out-proj R14 frozen.
// ---------------------------------------------------------------------------

#define B_  16
#define T_  512
#define C_  1024
#define H_  16
#define HD_ 64

typedef __bf16 bf16x8 __attribute__((ext_vector_type(8)));
typedef float  f32x4  __attribute__((ext_vector_type(4)));

__device__ __forceinline__ void gload16(const void* g, void* lds_dst) {
  __builtin_amdgcn_global_load_lds(
      (const __attribute__((address_space(1))) unsigned int*)g,
      (__attribute__((address_space(3))) unsigned int*)lds_dst, 16, 0, 0);
}

// ---------------------------------------------------------------------------
// prep: fused  x fp32->bf16  |  w_qkv^T  |  w_o^T   (one dispatch)
// blocks [0,4096): cvt 2048 elems each; [4096,7168): tconv wqkv (96x32);
// [7168,8192): tconv wo (32x32). 256 threads.
// ---------------------------------------------------------------------------
__global__ __launch_bounds__(256) void prep_kernel(
    const float* __restrict__ x, __bf16* __restrict__ xb,
    const float* __restrict__ wqkv, __bf16* __restrict__ wqt,
    const float* __restrict__ wo, __bf16* __restrict__ wot)
{
  __shared__ float tile[32][33];
  const int bid = blockIdx.x, tid = threadIdx.x;

  if (bid < 4096) {                                // ---- cvt ----
    int i = bid * 2048 + tid * 8;
    float4 f0 = *(const float4*)&x[i];
    float4 f1 = *(const float4*)&x[i + 4];
    bf16x8 o;
    o[0] = (__bf16)f0.x; o[1] = (__bf16)f0.y; o[2] = (__bf16)f0.z; o[3] = (__bf16)f0.w;
    o[4] = (__bf16)f1.x; o[5] = (__bf16)f1.y; o[6] = (__bf16)f1.z; o[7] = (__bf16)f1.w;
    *(bf16x8*)&xb[i] = o;
    return;
  }

  const float* w; __bf16* wt; int K, N, bx, by;
  if (bid < 7168) {                                // ---- tconv wqkv ----
    int b2 = bid - 4096;                           // 96 x 32
    w = wqkv; wt = wqt; K = C_; N = 3 * C_;
    bx = b2 % 96; by = b2 / 96;
  } else {                                         // ---- tconv wo ----
    int b3 = bid - 7168;                           // 32 x 32
    w = wo; wt = wot; K = C_; N = C_;
    bx = b3 % 32; by = b3 / 32;
  }
  const int tx = tid & 31, ty = tid >> 5;          // (32,8)
  const int n0 = bx * 32, k0 = by * 32;
  #pragma unroll
  for (int i = 0; i < 4; ++i) {
    int r = ty + i * 8;
    tile[r][tx] = w[(size_t)(k0 + r) * N + n0 + tx];
  }
  __syncthreads();
  #pragma unroll
  for (int i = 0; i < 4; ++i) {
    int r = ty + i * 8;
    wt[(size_t)(n0 + r) * K + k0 + tx] = (__bf16)tile[tx][r];
  }
}

// ---------------------------------------------------------------------------
// QKV GEMM (m97 structure, proven 60us). V written directly as V^T
// [B,H,HD,T]. Q written PRE-SCALED by 2^-5 * log2(e).
// ---------------------------------------------------------------------------
__global__ __launch_bounds__(256) void gemmsq_kernel(
    const __bf16* __restrict__ A, const __bf16* __restrict__ BT,
    const float* __restrict__ bias, int K, int NBn,
    __bf16* __restrict__ oq, __bf16* __restrict__ okk, __bf16* __restrict__ ovt)
{
  __shared__ __attribute__((aligned(16))) char lds[32768];   // A 16KB | B 16KB
  const int tid = threadIdx.x, lane = tid & 63, wid = tid >> 6;  // 4 waves
  const int wm = wid >> 1, wn = wid & 1;          // 2M x 2N
  const int lr = lane & 15, lg = lane >> 4;

  const int cpx = gridDim.x >> 3;                 // bijective XCD swizzle
  const int id = (blockIdx.x & 7) * cpx + (blockIdx.x >> 3);
  const int m0 = (id / NBn) * 128, n0 = (id % NBn) * 128;

  const int r8  = wid * 8 + (lane >> 3);          // 0..31
  const int csw = ((lane & 7) ^ (lane >> 3)) * 8; // pre-swizzled col (elems)

  auto stage = [&](const __bf16* g, char* dst) {  // 128x64 tile, 4 issues
    #pragma unroll
    for (int i = 0; i < 4; ++i)
      gload16(g + (size_t)(i * 32 + r8) * K + csw, dst + i * 4096 + wid * 1024);
  };
  auto rd = [&](bf16x8* d, const char* buf, int woff) {   // 8 x ds_read_b128
    #pragma unroll
    for (int f = 0; f < 4; ++f) {
      const char* rp = buf + (woff + f * 16 + lr) * 128;
      #pragma unroll
      for (int ks = 0; ks < 2; ++ks)
        d[f * 2 + ks] = *(const bf16x8*)(rp + (((ks << 2) + lg) ^ (lr & 7)) * 16);
    }
  };

  f32x4 acc[4][4] = {};
  const int nt = K >> 6;                          // 16
  const __bf16* gA = A  + (size_t)m0 * K;
  const __bf16* gB = BT + (size_t)n0 * K;
  char* const Ab = lds;
  char* const Bb = lds + 16384;

  stage(gA, Ab);
  stage(gB, Bb);
  asm volatile("s_waitcnt vmcnt(0)\ns_barrier" ::: "memory");

  bf16x8 a[8], b[8];
  for (int t = 0; t < nt; ++t) {
    rd(a, Ab, wm * 64);
    rd(b, Bb, wn * 64);
    asm volatile("s_waitcnt lgkmcnt(0)\ns_barrier" ::: "memory");
    if (t + 1 < nt) {
      stage(gA + (size_t)(t + 1) * 64, Ab);
      stage(gB + (size_t)(t + 1) * 64, Bb);
    }
    __builtin_amdgcn_s_setprio(1);
    #pragma unroll
    for (int mf = 0; mf < 4; ++mf)
      #pragma unroll
      for (int nf = 0; nf < 4; ++nf)
        #pragma unroll
        for (int ks = 0; ks < 2; ++ks)
          acc[mf][nf] = __builtin_amdgcn_mfma_f32_16x16x32_bf16(
              a[mf * 2 + ks], b[nf * 2 + ks], acc[mf][nf], 0, 0, 0);
    __builtin_amdgcn_s_setprio(0);
    asm volatile("s_waitcnt vmcnt(0)\ns_barrier" ::: "memory");
  }

  const float QSC = 0.04508422f;                  // 2^-5 * log2(e)
  #pragma unroll
  for (int nf = 0; nf < 4; ++nf) {
    int n = n0 + wn * 64 + nf * 16 + lr;
    float bv = bias[n];
    int which = n >> 10;
    int h = (n >> 6) & 15, d = n & 63;
    if (which == 2) {
      #pragma unroll
      for (int mf = 0; mf < 4; ++mf) {
        int m = m0 + wm * 64 + mf * 16 + lg * 4;      // j=0 row
        int bb = m >> 9, t0 = m & 511;
        ushort4 pk;
        __bf16 e0 = (__bf16)(acc[mf][nf][0] + bv);
        __bf16 e1 = (__bf16)(acc[mf][nf][1] + bv);
        __bf16 e2 = (__bf16)(acc[mf][nf][2] + bv);
        __bf16 e3 = (__bf16)(acc[mf][nf][3] + bv);
        pk.x = *(unsigned short*)&e0; pk.y = *(unsigned short*)&e1;
        pk.z = *(unsigned short*)&e2; pk.w = *(unsigned short*)&e3;
        *(ushort4*)&ovt[(size_t)((bb * H_ + h) * HD_ + d) * T_ + t0] = pk;
      }
    } else {
      __bf16* dst = (which == 0) ? oq : okk;
      const float scl = (which == 0) ? QSC : 1.0f;
      #pragma unroll
      for (int mf = 0; mf < 4; ++mf)
        #pragma unroll
        for (int j = 0; j < 4; ++j) {
          int m = m0 + wm * 64 + mf * 16 + lg * 4 + j;
          int bb = m >> 9, tt = m & 511;
          dst[(size_t)((bb * H_ + h) * T_ + tt) * HD_ + d] =
              (__bf16)((acc[mf][nf][j] + bv) * scl);
        }
    }
  }
}

// ---------------------------------------------------------------------------
// Out-proj GEMM (R14-frozen): tile 64x128, 4 waves, LDS 24KB, grid 1024.
// ---------------------------------------------------------------------------
__global__ __launch_bounds__(256) void gemmsq_o_kernel(
    const __bf16* __restrict__ A, const __bf16* __restrict__ BT,
    const float* __restrict__ bias, int K, int NBn, int N,
    float* __restrict__ out32)
{
  __shared__ __attribute__((aligned(16))) char lds[24576];   // A 8KB | B 16KB
  const int tid = threadIdx.x, lane = tid & 63, wid = tid >> 6;
  const int wm = wid >> 1, wn = wid & 1;          // 2M x 2N
  const int lr = lane & 15, lg = lane >> 4;

  const int cpx = gridDim.x >> 3;
  const int id = (blockIdx.x & 7) * cpx + (blockIdx.x >> 3);
  const int m0 = (id / NBn) * 64, n0 = (id % NBn) * 128;

  const int r8  = wid * 8 + (lane >> 3);          // 0..31
  const int csw = ((lane & 7) ^ (lane >> 3)) * 8;

  auto stageA = [&](const __bf16* g, char* dst) { // 64x64 tile, 2 issues
    #pragma unroll
    for (int i = 0; i < 2; ++i)
      gload16(g + (size_t)(i * 32 + r8) * K + csw, dst + i * 4096 + wid * 1024);
  };
  auto stageB = [&](const __bf16* g, char* dst) { // 128x64 tile, 4 issues
    #pragma unroll
    for (int i = 0; i < 4; ++i)
      gload16(g + (size_t)(i * 32 + r8) * K + csw, dst + i * 4096 + wid * 1024);
  };
  auto rdA = [&](bf16x8* d, const char* buf) {    // 4 x ds_read_b128
    #pragma unroll
    for (int f = 0; f < 2; ++f) {
      const char* rp = buf + (wm * 32 + f * 16 + lr) * 128;
      #pragma unroll
      for (int ks = 0; ks < 2; ++ks)
        d[f * 2 + ks] = *(const bf16x8*)(rp + (((ks << 2) + lg) ^ (lr & 7)) * 16);
    }
  };
  auto rdB = [&](bf16x8* d, const char* buf) {    // 8 x ds_read_b128
    #pragma unroll
    for (int f = 0; f < 4; ++f) {
      const char* rp = buf + (wn * 64 + f * 16 + lr) * 128;
      #pragma unroll
      for (int ks = 0; ks < 2; ++ks)
        d[f * 2 + ks] = *(const bf16x8*)(rp + (((ks << 2) + lg) ^ (lr & 7)) * 16);
    }
  };

  f32x4 acc[2][4] = {};
  const int nt = K >> 6;
  const __bf16* gA = A  + (size_t)m0 * K;
  const __bf16* gB = BT + (size_t)n0 * K;
  char* const Ab = lds;
  char* const Bb = lds + 8192;

  stageA(gA, Ab);
  stageB(gB, Bb);
  asm volatile("s_waitcnt vmcnt(0)\ns_barrier" ::: "memory");

  bf16x8 a[4], b[8];
  for (int t = 0; t < nt; ++t) {
    rdA(a, Ab);
    rdB(b, Bb);
    asm volatile("s_waitcnt lgkmcnt(0)\ns_barrier" ::: "memory");
    if (t + 1 < nt) {
      stageA(gA + (size_t)(t + 1) * 64, Ab);
      stageB(gB + (size_t)(t + 1) * 64, Bb);
    }
    __builtin_amdgcn_s_setprio(1);
    #pragma unroll
    for (int mf = 0; mf < 2; ++mf)
      #pragma unroll
      for (int nf = 0; nf < 4; ++nf)
        #pragma unroll
        for (int ks = 0; ks < 2; ++ks)
          acc[mf][nf] = __builtin_amdgcn_mfma_f32_16x16x32_bf16(
              a[mf * 2 + ks], b[nf * 2 + ks], acc[mf][nf], 0, 0, 0);
    __builtin_amdgcn_s_setprio(0);
    asm volatile("s_waitcnt vmcnt(0)\ns_barrier" ::: "memory");
  }

  #pragma unroll
  for (int nf = 0; nf < 4; ++nf) {
    int n = n0 + wn * 64 + nf * 16 + lr;
    float bv = bias[n];
    #pragma unroll
    for (int mf = 0; mf < 2; ++mf)
      #pragma unroll
      for (int j = 0; j < 4; ++j) {
        int m = m0 + wm * 32 + mf * 16 + lg * 4 + j;
        out32[(size_t)m * N + n] = acc[mf][nf][j] + bv;
      }
  }
}

// ---------------------------------------------------------------------------
// Flash attention (causal), full-LDS per-head (R13-frozen).
// ---------------------------------------------------------------------------
__global__ __launch_bounds__(512) void attn_kernel(
    const __bf16* __restrict__ qb, const __bf16* __restrict__ kb,
    const __bf16* __restrict__ vtb, __bf16* __restrict__ y)
{
  extern __shared__ __align__(16) char smem[];
  char* const Ksb = smem;                         // 64KB  K  [512][64]
  char* const Vtb = smem + 65536;                 // 64KB  V^T [64][512]
  char* const Psb = smem + 131072;                // 32KB  [8w][2g][16][64] swz

  const int tid = threadIdx.x, lane = tid & 63, w = tid >> 6;   // 8 waves
  const int lr = lane & 15, lg = lane >> 4;
  const int bh = blockIdx.x;
  const size_t base = (size_t)bh * T_ * HD_;
  const int b = bh >> 4, h = bh & 15;

  {
    const int rk = tid >> 3;
    const int sk = (tid & 7) ^ (rk & 7);
    const int rv = tid >> 6;
    const int sv = (tid & 63) ^ rv;
    #pragma unroll
    for (int i = 0; i < 8; ++i) {
      gload16(kb  + base + (size_t)(i * 64 + rk) * HD_ + sk * 8,
              Ksb + i * 8192 + w * 1024);
      gload16(vtb + base + (size_t)(i * 8 + rv) * T_ + sv * 8,
              Vtb + i * 8192 + w * 1024);
    }
  }
  asm volatile("s_waitcnt vmcnt(0)\ns_barrier" ::: "memory");

  bf16x8 onesf;
  #pragma unroll
  for (int i = 0; i < 8; ++i) onesf[i] = (__bf16)1.0f;

  char* const PsW0 = Psb + (w * 2 + 0) * 2048;
  char* const PsW1 = Psb + (w * 2 + 1) * 2048;

  #pragma unroll 1
  for (int sw = 0; sw < 2; ++sw) {
    const int GA = sw * 16 + w;
    const int GB = sw * 16 + 15 - w;
    const int q0A = GA * 16, q0B = GB * 16;
    const int cA = GA >> 2, cB = GB >> 2;

    bf16x8 qfA[2], qfB[2];
    #pragma unroll
    for (int s = 0; s < 2; ++s) {
      qfA[s] = *(const bf16x8*)&qb[base + (size_t)(q0A + lr) * HD_ + s * 32 + lg * 8];
      qfB[s] = *(const bf16x8*)&qb[base + (size_t)(q0B + lr) * HD_ + s * 32 + lg * 8];
    }

    f32x4 accA[4] = {}, accB[4] = {};
    f32x4 saccA = {}, saccB = {};

    for (int c = 0; c <= cB; ++c) {
      const bool actA = (c <= cA);

      bf16x8 kf[2][4];
      #pragma unroll
      for (int s = 0; s < 2; ++s)
        #pragma unroll
        for (int cc = 0; cc < 4; ++cc)
          kf[s][cc] = *(const bf16x8*)(Ksb + (size_t)(c * 64 + cc * 16 + lr) * 128
                                       + (((s << 2) + lg) ^ (lr & 7)) * 16);

      #pragma unroll
      for (int g = 0; g < 2; ++g) {
        if (g == 0 && !actA) continue;
        const bf16x8* qf = (g == 0) ? qfA : qfB;
        const int q0 = (g == 0) ? q0A : q0B;
        const int cg = (g == 0) ? cA : cB;
        char* PsW = (g == 0) ? PsW0 : PsW1;

        f32x4 sc[4] = {};
        __builtin_amdgcn_s_setprio(1);
        #pragma unroll
        for (int s = 0; s < 2; ++s)
          #pragma unroll
          for (int cc = 0; cc < 4; ++cc)
            sc[cc] = __builtin_amdgcn_mfma_f32_16x16x32_bf16(
                kf[s][cc], qf[s], sc[cc], 0, 0, 0);
        __builtin_amdgcn_s_setprio(0);

        #pragma unroll
        for (int cc = 0; cc < 4; ++cc) {
          float p[4];
          #pragma unroll
          for (int j = 0; j < 4; ++j) {
            float v = exp2f(sc[cc][j]);
            if (c == cg) {
              int kv = c * 64 + cc * 16 + lg * 4 + j;
              if (kv > q0 + lr) v = 0.f;
            }
            p[j] = v;
          }
          ushort4 pkw;
          __bf16 e0 = (__bf16)p[0], e1 = (__bf16)p[1];
          __bf16 e2 = (__bf16)p[2], e3 = (__bf16)p[3];
          pkw.x = *(unsigned short*)&e0; pkw.y = *(unsigned short*)&e1;
          pkw.z = *(unsigned short*)&e2; pkw.w = *(unsigned short*)&e3;
          int g16 = (2 * cc + (lg >> 1)) ^ (lr & 7);
          *(ushort4*)(PsW + lr * 128 + g16 * 16 + (lg & 1) * 8) = pkw;
        }
      }

      bf16x8 vf[2][4];
      #pragma unroll
      for (int s = 0; s < 2; ++s)
        #pragma unroll
        for (int dd = 0; dd < 4; ++dd)
          vf[s][dd] = *(const bf16x8*)(Vtb + (size_t)(dd * 16 + lr) * 1024
                                       + (8 * c + (((s << 2) + lg) ^ (lr & 7))) * 16);

      __builtin_amdgcn_s_setprio(1);
      #pragma unroll
      for (int g = 0; g < 2; ++g) {
        if (g == 0 && !actA) continue;
        char* PsW = (g == 0) ? PsW0 : PsW1;
        f32x4* acc = (g == 0) ? accA : accB;
        f32x4& sacc = (g == 0) ? saccA : saccB;
        #pragma unroll
        for (int s = 0; s < 2; ++s) {
          bf16x8 pa = *(const bf16x8*)(PsW + lr * 128
                                       + (((s << 2) + lg) ^ (lr & 7)) * 16);
          sacc = __builtin_amdgcn_mfma_f32_16x16x32_bf16(pa, onesf, sacc, 0, 0, 0);
          #pragma unroll
          for (int dd = 0; dd < 4; ++dd)
            acc[dd] = __builtin_amdgcn_mfma_f32_16x16x32_bf16(
                pa, vf[s][dd], acc[dd], 0, 0, 0);
        }
      }
      __builtin_amdgcn_s_setprio(0);
    }

    #pragma unroll
    for (int g = 0; g < 2; ++g) {
      const int q0 = (g == 0) ? q0A : q0B;
      f32x4* acc = (g == 0) ? accA : accB;
      f32x4& sacc = (g == 0) ? saccA : saccB;
      float inv[4];
      #pragma unroll
      for (int j = 0; j < 4; ++j) inv[j] = 1.f / sacc[j];
      #pragma unroll
      for (int dd = 0; dd < 4; ++dd)
        #pragma unroll
        for (int j = 0; j < 4; ++j) {
          int t = q0 + lg * 4 + j;
          int d = dd * 16 + lr;
          y[((size_t)(b * T_ + t)) * C_ + h * HD_ + d] = (__bf16)(acc[dd][j] * inv[j]);
        }
    }
  }
}

// ---------------------------------------------------------------------------
extern "C" void kernel_launch(void* const* d_in, const int* in_sizes, int n_in,
                              void* d_out, int out_size, void* d_ws, size_t ws_size,
                              hipStream_t stream) {
  const float* x    = (const float*)d_in[0];
  const float* wqkv = (const float*)d_in[1];
  const float* bqkv = (const float*)d_in[2];
  const float* wo   = (const float*)d_in[3];
  const float* bo   = (const float*)d_in[4];
  float* out = (float*)d_out;

  char* ws = (char*)d_ws;
  const size_t MB = 1u << 20;
  __bf16* xb    = (__bf16*)(ws);              // 16 MB  x bf16 [8192][1024]
  __bf16* wqt   = (__bf16*)(ws + 16 * MB);    //  6 MB  w_qkv^T bf16 [3072][1024]
  __bf16* wot   = (__bf16*)(ws + 22 * MB);    //  2 MB  w_o^T bf16 [1024][1024]
  __bf16* qbuf  = (__bf16*)(ws + 24 * MB);    // 16 MB  Q' [B,H,T,HD] (pre-scaled)
  __bf16* kbuf  = (__bf16*)(ws + 40 * MB);    // 16 MB  K [B,H,T,HD]
  __bf16* vtbuf = (__bf16*)(ws + 56 * MB);    // 16 MB  V^T [B,H,HD,T] (direct)
  __bf16* ybuf  = (__bf16*)(ws + 72 * MB);    // 16 MB  attn out [B,T,C]

  (void)hipFuncSetAttribute(reinterpret_cast<const void*>(&attn_kernel),
                            hipFuncAttributeMaxDynamicSharedMemorySize, 163840);

  // fused prep: cvt (4096 blocks) + tconv wqkv (3072) + tconv wo (1024)
  prep_kernel<<<8192, 256, 0, stream>>>(x, xb, wqkv, wqt, wo, wot);

  // QKV: 64 x 24 -> 1536 blocks; V written transposed, Q pre-scaled
  gemmsq_kernel<<<1536, 256, 0, stream>>>(
      xb, wqt, bqkv, C_, 24, qbuf, kbuf, vtbuf);

  // attention: one block/head, full K/V^T in LDS, batched swapped-QK waves
  attn_kernel<<<256, 512, 163840, stream>>>(qbuf, kbuf, vtbuf, ybuf);

  // out-proj: 128 x 8 -> 1024 blocks (64x128 tile)
  gemmsq_o_kernel<<<1024, 256, 0, stream>>>(
      ybuf, wot, bo, C_, 8, C_, out);
}